// Round 4
// baseline (274.450 us; speedup 1.0000x reference)
//
#include <hip/hip_runtime.h>

// DCNv2 fused v4: tap-outer K-loop. Per tap: stage w[k][128o][128c] bf16 into
// LDS (XOR-swizzled 16B segments, conflict-free, register-prefetched 1-2 taps
// ahead) -> 17 barriers total. Corner rows read once per tap for all 4 cb
// chunks (rolling 2-deep register pipeline). MFMA f32_16x16x32_bf16.
// Pre-work (x transpose to [n][hw][c] bf16 + weight recast wt[k][o][c]) fused
// into one kernel.

#define NI 8
#define CI 128
#define HI 96
#define WI 96
#define CO 128
#define K2 9
#define P_TOT 9216
#define TP 64
#define NTILE 144                                   // P_TOT/TP
#define CPAD 40
#define XT_ELEMS ((size_t)NI * P_TOT * CI)          // 9,437,184 bf16
#define WT_ELEMS ((size_t)K2 * CO * CI)             // 147,456 bf16
#define WS_NEED ((XT_ELEMS + WT_ELEMS) * 2)

typedef short short8 __attribute__((ext_vector_type(8)));
typedef float f32x4 __attribute__((ext_vector_type(4)));

static __device__ __forceinline__ ushort bf16_rne(float x) {
    unsigned u = __float_as_uint(x);
    u = (u + 0x7FFF + ((u >> 16) & 1)) >> 16;
    return (ushort)u;
}
static __device__ __forceinline__ unsigned pack_bf2(float a, float b) {
    return (unsigned)bf16_rne(a) | ((unsigned)bf16_rne(b) << 16);
}
static __device__ __forceinline__ float bflo(unsigned u) { return __uint_as_float(u << 16); }
static __device__ __forceinline__ float bfhi(unsigned u) { return __uint_as_float(u & 0xFFFF0000u); }

union U4S8 { uint4 u; short8 s; };

// ---- fused pre-kernel: grid = 1152 (transpose) + 64 (weight recast) ----
__global__ __launch_bounds__(256)
void pre_kernel(const float* __restrict__ x, const float* __restrict__ w,
                ushort* __restrict__ xt, ushort* __restrict__ wt) {
    const int bid = blockIdx.x;
    const int tid = threadIdx.x;
    if (bid < NI * NTILE) {
        // transpose x[n][c][hw] fp32 -> xt[n][hw][c] bf16
        __shared__ ushort tile[64][132];
        const int n = bid / NTILE, t = bid % NTILE;
        const int hw0 = t * 64;
        #pragma unroll
        for (int rep = 0; rep < 8; ++rep) {
            int idx = rep * 256 + tid;              // < 2048
            int c = idx >> 4, iq = idx & 15;
            float4 f = *(const float4*)(x + ((size_t)(n * CI + c)) * P_TOT + hw0 + iq * 4);
            tile[iq * 4 + 0][c] = bf16_rne(f.x);
            tile[iq * 4 + 1][c] = bf16_rne(f.y);
            tile[iq * 4 + 2][c] = bf16_rne(f.z);
            tile[iq * 4 + 3][c] = bf16_rne(f.w);
        }
        __syncthreads();
        #pragma unroll
        for (int rep = 0; rep < 8; ++rep) {
            int idx = rep * 256 + tid;              // < 2048
            int i = idx >> 5, cq = idx & 31;
            uint2 v = *(const uint2*)&tile[i][cq * 4];
            *(uint2*)(xt + ((size_t)n * P_TOT + hw0 + i) * CI + cq * 4) = v;
        }
    } else {
        // wt[k][o][c] bf16 from weight[o][c][k] fp32
        const int b2 = bid - NI * NTILE;            // 0..63
        #pragma unroll
        for (int j = 0; j < 9; ++j) {
            int idx = j * 16384 + b2 * 256 + tid;   // < 147456
            int k   = idx >> 14;
            int rem = idx & 16383;
            int o = rem >> 7, c = rem & 127;
            wt[idx] = bf16_rne(w[(size_t)o * (CI * K2) + c * K2 + k]);
        }
    }
}

__global__ __launch_bounds__(256, 3)
void dcn_mfma3_kernel(const ushort* __restrict__ xt,
                      const ushort* __restrict__ wt,
                      const float* __restrict__ offset,
                      const float* __restrict__ mask,
                      const float* __restrict__ bias,
                      float* __restrict__ out)
{
    __shared__ uint2  s_midx[K2 * TP];      // packed corner row indices (u16 x4)
    __shared__ float4 s_mw[K2 * TP];        // bilinear*mask weights (fp32)
    __shared__ ushort s_w[CO * CI];         // one tap: 128o x 128c, XOR-swizzled

    const int tid  = threadIdx.x;
    const int bid  = blockIdx.x;
    const int n    = bid & 7;               // XCD swizzle
    const int p0   = (bid >> 3) * TP;
    const int wave = tid >> 6;
    const int lane = tid & 63;
    const int l15  = lane & 15;
    const int quad = lane >> 4;

    uint4 sreg[8];
    auto load_stage = [&](int k) {
        #pragma unroll
        for (int j = 0; j < 8; ++j) {
            int item = j * 256 + tid;       // linear: o*16+cs -> offset item*16B
            sreg[j] = *(const uint4*)(wt + (size_t)k * (CO * CI) + (size_t)item * 8);
        }
    };
    auto write_stage = [&]() {
        #pragma unroll
        for (int j = 0; j < 8; ++j) {
            int item = j * 256 + tid;
            int o = item >> 4, cs = item & 15;
            *(uint4*)&s_w[o * CI + (cs ^ (o & 7)) * 8] = sreg[j];
        }
    };

    load_stage(0);

    // ---- meta phase ----
    for (int it = 0; it < 3; ++it) {
        int item = it * 256 + tid;          // k*TP + i, < 576
        if (item < K2 * TP) {
            int k = item / TP;
            int i = item % TP;
            int p  = p0 + i;
            int ph = p / WI;
            int pw = p % WI;
            float offy = offset[((size_t)n * (2 * K2) + 2 * k    ) * P_TOT + p];
            float offx = offset[((size_t)n * (2 * K2) + 2 * k + 1) * P_TOT + p];
            float m    = mask  [((size_t)n * K2 + k) * P_TOT + p];
            int ky = k / 3, kx = k % 3;
            float py = (float)(ph - 1 + ky) + offy;
            float px = (float)(pw - 1 + kx) + offx;
            float y0f = floorf(py), x0f = floorf(px);
            float wy = py - y0f, wx = px - x0f;
            int y0 = (int)y0f, x0 = (int)x0f;
            int y1 = y0 + 1,  x1 = x0 + 1;
            bool vy0 = (y0 >= 0) && (y0 < HI);
            bool vy1 = (y1 >= 0) && (y1 < HI);
            bool vx0 = (x0 >= 0) && (x0 < WI);
            bool vx1 = (x1 >= 0) && (x1 < WI);
            unsigned i00 = (vy0 && vx0) ? (unsigned)(y0 * WI + x0) : 0u;
            unsigned i01 = (vy0 && vx1) ? (unsigned)(y0 * WI + x1) : 0u;
            unsigned i10 = (vy1 && vx0) ? (unsigned)(y1 * WI + x0) : 0u;
            unsigned i11 = (vy1 && vx1) ? (unsigned)(y1 * WI + x1) : 0u;
            float w00 = (vy0 && vx0) ? (1.f - wy) * (1.f - wx) * m : 0.f;
            float w01 = (vy0 && vx1) ? (1.f - wy) * wx          * m : 0.f;
            float w10 = (vy1 && vx0) ? wy * (1.f - wx)          * m : 0.f;
            float w11 = (vy1 && vx1) ? wy * wx                  * m : 0.f;
            s_midx[item] = make_uint2(i00 | (i01 << 16), i10 | (i11 << 16));
            s_mw[item]   = make_float4(w00, w01, w10, w11);
        }
    }

    write_stage();      // tap 0 -> LDS
    load_stage(1);      // prefetch tap 1 (in flight across barrier + compute)
    __syncthreads();    // meta + s_w(tap0) visible

    f32x4 acc[8];
    #pragma unroll
    for (int a = 0; a < 8; ++a) acc[a] = (f32x4){0.f, 0.f, 0.f, 0.f};

    const ushort* xb = xt + (size_t)n * (P_TOT * CI) + quad * 8;

    for (int k = 0; k < K2; ++k) {
        uint2  mi = s_midx[k * TP + wave * 16 + l15];
        float4 mw = s_mw[k * TP + wave * 16 + l15];
        const ushort* c00 = xb + (size_t)(mi.x & 0xFFFF) * CI;
        const ushort* c01 = xb + (size_t)(mi.x >> 16)    * CI;
        const ushort* c10 = xb + (size_t)(mi.y & 0xFFFF) * CI;
        const ushort* c11 = xb + (size_t)(mi.y >> 16)    * CI;

        uint4 ra[4], rb[4];
        ra[0] = *(const uint4*)(c00);      ra[1] = *(const uint4*)(c01);
        ra[2] = *(const uint4*)(c10);      ra[3] = *(const uint4*)(c11);
        rb[0] = *(const uint4*)(c00 + 32); rb[1] = *(const uint4*)(c01 + 32);
        rb[2] = *(const uint4*)(c10 + 32); rb[3] = *(const uint4*)(c11 + 32);

        #pragma unroll
        for (int cb = 0; cb < 4; ++cb) {
            uint4 r0 = (cb & 1) ? rb[0] : ra[0];
            uint4 r1 = (cb & 1) ? rb[1] : ra[1];
            uint4 r2 = (cb & 1) ? rb[2] : ra[2];
            uint4 r3 = (cb & 1) ? rb[3] : ra[3];
            float v0 = mw.x * bflo(r0.x) + mw.y * bflo(r1.x) + mw.z * bflo(r2.x) + mw.w * bflo(r3.x);
            float v1 = mw.x * bfhi(r0.x) + mw.y * bfhi(r1.x) + mw.z * bfhi(r2.x) + mw.w * bfhi(r3.x);
            float v2 = mw.x * bflo(r0.y) + mw.y * bflo(r1.y) + mw.z * bflo(r2.y) + mw.w * bflo(r3.y);
            float v3 = mw.x * bfhi(r0.y) + mw.y * bfhi(r1.y) + mw.z * bfhi(r2.y) + mw.w * bfhi(r3.y);
            float v4 = mw.x * bflo(r0.z) + mw.y * bflo(r1.z) + mw.z * bflo(r2.z) + mw.w * bflo(r3.z);
            float v5 = mw.x * bfhi(r0.z) + mw.y * bfhi(r1.z) + mw.z * bfhi(r2.z) + mw.w * bfhi(r3.z);
            float v6 = mw.x * bflo(r0.w) + mw.y * bflo(r1.w) + mw.z * bflo(r2.w) + mw.w * bflo(r3.w);
            float v7 = mw.x * bfhi(r0.w) + mw.y * bfhi(r1.w) + mw.z * bfhi(r2.w) + mw.w * bfhi(r3.w);
            // refill consumed buffer with cb+2 (WAR resolved by register dep)
            if (cb == 0) {
                ra[0] = *(const uint4*)(c00 + 64); ra[1] = *(const uint4*)(c01 + 64);
                ra[2] = *(const uint4*)(c10 + 64); ra[3] = *(const uint4*)(c11 + 64);
            } else if (cb == 1) {
                rb[0] = *(const uint4*)(c00 + 96); rb[1] = *(const uint4*)(c01 + 96);
                rb[2] = *(const uint4*)(c10 + 96); rb[3] = *(const uint4*)(c11 + 96);
            }
            U4S8 cvt;
            cvt.u.x = pack_bf2(v0, v1);
            cvt.u.y = pack_bf2(v2, v3);
            cvt.u.z = pack_bf2(v4, v5);
            cvt.u.w = pack_bf2(v6, v7);
            short8 bfr = cvt.s;
            #pragma unroll
            for (int ot = 0; ot < 8; ++ot) {
                int o = ot * 16 + l15;
                short8 afr = *(const short8*)&s_w[o * CI + (((cb * 4 + quad) ^ (o & 7)) * 8)];
                acc[ot] = __builtin_amdgcn_mfma_f32_16x16x32_bf16(afr, bfr, acc[ot], 0, 0, 0);
            }
        }

        if (k < 8) {
            __syncthreads();        // all waves done reading s_w(tap k)
            write_stage();          // tap k+1 -> LDS
            if (k < 7) load_stage(k + 2);
            __syncthreads();        // s_w(tap k+1) visible
        }
    }

    // ---- epilogue ----
    #pragma unroll
    for (int ot = 0; ot < 8; ++ot) {
        #pragma unroll
        for (int r = 0; r < 4; ++r) {
            int o = ot * 16 + quad * 4 + r;
            int p = p0 + wave * 16 + l15;
            out[((size_t)n * CO + o) * P_TOT + p] = acc[ot][r] + bias[o];
        }
    }
}

// ---------------- fallback (no workspace): round-2 structure ----------------
__global__ __launch_bounds__(256, 3)
void dcn_fallback_kernel(const float* __restrict__ x,
                         const float* __restrict__ offset,
                         const float* __restrict__ mask,
                         const float* __restrict__ weight,
                         const float* __restrict__ bias,
                         float* __restrict__ out)
{
    __shared__ uint2  s_midx[K2 * TP];
    __shared__ float4 s_mw[K2 * TP];
    __shared__ ushort s_v[TP * CPAD];
    __shared__ ushort s_w[CO * CPAD];

    const int tid  = threadIdx.x;
    const int bid  = blockIdx.x;
    const int n    = bid & 7;
    const int p0   = (bid >> 3) * TP;

    for (int it = 0; it < 3; ++it) {
        int item = it * 256 + tid;
        if (item < K2 * TP) {
            int k = item / TP;
            int i = item % TP;
            int p  = p0 + i;
            int ph = p / WI;
            int pw = p % WI;
            float offy = offset[((size_t)n * (2 * K2) + 2 * k    ) * P_TOT + p];
            float offx = offset[((size_t)n * (2 * K2) + 2 * k + 1) * P_TOT + p];
            float m    = mask  [((size_t)n * K2 + k) * P_TOT + p];
            int ky = k / 3, kx = k % 3;
            float py = (float)(ph - 1 + ky) + offy;
            float px = (float)(pw - 1 + kx) + offx;
            float y0f = floorf(py), x0f = floorf(px);
            float wy = py - y0f, wx = px - x0f;
            int y0 = (int)y0f, x0 = (int)x0f;
            int y1 = y0 + 1,  x1 = x0 + 1;
            bool vy0 = (y0 >= 0) && (y0 < HI);
            bool vy1 = (y1 >= 0) && (y1 < HI);
            bool vx0 = (x0 >= 0) && (x0 < WI);
            bool vx1 = (x1 >= 0) && (x1 < WI);
            unsigned i00 = (vy0 && vx0) ? (unsigned)(y0 * WI + x0) : 0u;
            unsigned i01 = (vy0 && vx1) ? (unsigned)(y0 * WI + x1) : 0u;
            unsigned i10 = (vy1 && vx0) ? (unsigned)(y1 * WI + x0) : 0u;
            unsigned i11 = (vy1 && vx1) ? (unsigned)(y1 * WI + x1) : 0u;
            float w00 = (vy0 && vx0) ? (1.f - wy) * (1.f - wx) * m : 0.f;
            float w01 = (vy0 && vx1) ? (1.f - wy) * wx          * m : 0.f;
            float w10 = (vy1 && vx0) ? wy * (1.f - wx)          * m : 0.f;
            float w11 = (vy1 && vx1) ? wy * wx                  * m : 0.f;
            s_midx[item] = make_uint2(i00 | (i01 << 16), i10 | (i11 << 16));
            s_mw[item]   = make_float4(w00, w01, w10, w11);
        }
    }
    __syncthreads();

    const int wave = tid >> 6;
    const int lane = tid & 63;
    const int l15  = lane & 15;
    const int quad = lane >> 4;
    const int o_base = (wave >> 1) * 64;
    const int p_base = (wave & 1) * 32;
    const int gp = tid & 63;
    const int cg = wave;

    f32x4 acc[4][2];
    #pragma unroll
    for (int a = 0; a < 4; ++a)
        #pragma unroll
        for (int b = 0; b < 2; ++b) acc[a][b] = (f32x4){0.f, 0.f, 0.f, 0.f};

    for (int cb = 0; cb < 4; ++cb) {
        for (int k = 0; k < K2; ++k) {
            {
                uint2  mi = s_midx[k * TP + gp];
                float4 mw = s_mw[k * TP + gp];
                int i00 = mi.x & 0xFFFF, i01 = mi.x >> 16;
                int i10 = mi.y & 0xFFFF, i11 = mi.y >> 16;
                const float* xb = x + ((size_t)(n * CI + cb * 32 + cg * 8)) * (HI * WI);
                float v[8];
                #pragma unroll
                for (int j = 0; j < 8; ++j) {
                    const float* xp = xb + (size_t)j * (HI * WI);
                    v[j] = mw.x * xp[i00] + mw.y * xp[i01]
                         + mw.z * xp[i10] + mw.w * xp[i11];
                }
                uint4 pk;
                pk.x = pack_bf2(v[0], v[1]);
                pk.y = pack_bf2(v[2], v[3]);
                pk.z = pack_bf2(v[4], v[5]);
                pk.w = pack_bf2(v[6], v[7]);
                *(uint4*)&s_v[gp * CPAD + cg * 8] = pk;
            }
            {
                int o = tid >> 1, half = tid & 1;
                const float* wsrc = weight + (size_t)o * (CI * K2)
                                  + (cb * 32 + half * 16) * K2 + k;
                ushort tmp[16];
                #pragma unroll
                for (int i = 0; i < 16; ++i) tmp[i] = bf16_rne(wsrc[i * K2]);
                *(uint4*)&s_w[o * CPAD + half * 16]     = *(uint4*)&tmp[0];
                *(uint4*)&s_w[o * CPAD + half * 16 + 8] = *(uint4*)&tmp[8];
            }
            __syncthreads();
            short8 afr[4], bfr[2];
            #pragma unroll
            for (int ot = 0; ot < 4; ++ot)
                afr[ot] = *(const short8*)&s_w[(o_base + ot * 16 + l15) * CPAD + quad * 8];
            #pragma unroll
            for (int pt = 0; pt < 2; ++pt)
                bfr[pt] = *(const short8*)&s_v[(p_base + pt * 16 + l15) * CPAD + quad * 8];
            #pragma unroll
            for (int ot = 0; ot < 4; ++ot)
                #pragma unroll
                for (int pt = 0; pt < 2; ++pt)
                    acc[ot][pt] = __builtin_amdgcn_mfma_f32_16x16x32_bf16(
                        afr[ot], bfr[pt], acc[ot][pt], 0, 0, 0);
            __syncthreads();
        }
    }

    #pragma unroll
    for (int ot = 0; ot < 4; ++ot)
        #pragma unroll
        for (int r = 0; r < 4; ++r) {
            int o = o_base + ot * 16 + quad * 4 + r;
            float b = bias[o];
            #pragma unroll
            for (int pt = 0; pt < 2; ++pt) {
                int p = p0 + p_base + pt * 16 + l15;
                out[((size_t)n * CO + o) * P_TOT + p] = acc[ot][pt][r] + b;
            }
        }
}

extern "C" void kernel_launch(void* const* d_in, const int* in_sizes, int n_in,
                              void* d_out, int out_size, void* d_ws, size_t ws_size,
                              hipStream_t stream) {
    const float* x      = (const float*)d_in[0];
    const float* offset = (const float*)d_in[1];
    const float* mask   = (const float*)d_in[2];
    const float* weight = (const float*)d_in[3];
    const float* bias   = (const float*)d_in[4];
    float* out = (float*)d_out;

    dim3 block(256);
    if (ws_size >= WS_NEED) {
        ushort* xt = (ushort*)d_ws;
        ushort* wt = xt + XT_ELEMS;
        pre_kernel<<<dim3(NI * NTILE + 64), block, 0, stream>>>(x, weight, xt, wt);
        dcn_mfma3_kernel<<<dim3(NI * NTILE), block, 0, stream>>>(
            xt, wt, offset, mask, bias, out);
    } else {
        dcn_fallback_kernel<<<dim3(NI * NTILE), block, 0, stream>>>(
            x, offset, mask, weight, bias, out);
    }
}

// Round 5
// 211.412 us; speedup vs baseline: 1.2982x; 1.2982x over previous
//
#include <hip/hip_runtime.h>

// DCNv2 fused v5: tap-outer K-loop, weights staged via global_load_lds
// (async DMA, zero VGPRs, dbuf, 9 barriers). wt is stored PRE-SWIZZLED in
// d_ws so the DMA's linear lane*16B fill produces the XOR-swizzled LDS
// layout (conflict-free ds_read_b128 A-frags, no padding). Register gather
// of B-frags from xt[n][hw][c] bf16 (rolling 2-deep pipeline) as in R4.

#define NI 8
#define CI 128
#define HI 96
#define WI 96
#define CO 128
#define K2 9
#define P_TOT 9216
#define TP 64
#define NTILE 144                                   // P_TOT/TP
#define CPAD 40
#define XT_ELEMS ((size_t)NI * P_TOT * CI)          // 9,437,184 bf16
#define WT_ELEMS ((size_t)K2 * CO * CI)             // 147,456 bf16
#define WS_NEED ((XT_ELEMS + WT_ELEMS) * 2)

typedef short short8 __attribute__((ext_vector_type(8)));
typedef float f32x4 __attribute__((ext_vector_type(4)));

static __device__ __forceinline__ ushort bf16_rne(float x) {
    unsigned u = __float_as_uint(x);
    u = (u + 0x7FFF + ((u >> 16) & 1)) >> 16;
    return (ushort)u;
}
static __device__ __forceinline__ unsigned pack_bf2(float a, float b) {
    return (unsigned)bf16_rne(a) | ((unsigned)bf16_rne(b) << 16);
}
static __device__ __forceinline__ float bflo(unsigned u) { return __uint_as_float(u << 16); }
static __device__ __forceinline__ float bfhi(unsigned u) { return __uint_as_float(u & 0xFFFF0000u); }

union U4S8 { uint4 u; short8 s; };

// async global->LDS, 16B per lane; LDS dest = wave-uniform base + lane*16
static __device__ __forceinline__ void gll16(const ushort* g, ushort* l) {
    __builtin_amdgcn_global_load_lds(
        (const __attribute__((address_space(1))) unsigned int*)g,
        (__attribute__((address_space(3))) unsigned int*)l, 16, 0, 0);
}

// ---- pre-kernel: grid = 576 (x transpose) + 72 (weight recast+swizzle) ----
__global__ __launch_bounds__(256)
void pre_kernel(const float* __restrict__ x, const float* __restrict__ w,
                ushort* __restrict__ xt, ushort* __restrict__ wt) {
    const int bid = blockIdx.x;
    const int tid = threadIdx.x;
    if (bid < 576) {
        // transpose x[n][c][hw] fp32 -> xt[n][hw][c] bf16; tile 64c x 256hw
        __shared__ ushort t[256][68];
        const int n = bid / 72, rr = bid % 72;
        const int cblk = rr & 1, hw0 = (rr >> 1) * 256;
        #pragma unroll
        for (int j = 0; j < 16; ++j) {
            int item = j * 256 + tid;               // < 4096
            int c = item >> 6, q = item & 63;
            float4 f = *(const float4*)(x + ((size_t)(n * CI + cblk * 64 + c)) * P_TOT
                                        + hw0 + q * 4);
            t[q * 4 + 0][c] = bf16_rne(f.x);
            t[q * 4 + 1][c] = bf16_rne(f.y);
            t[q * 4 + 2][c] = bf16_rne(f.z);
            t[q * 4 + 3][c] = bf16_rne(f.w);
        }
        __syncthreads();
        #pragma unroll
        for (int j = 0; j < 16; ++j) {
            int item = j * 256 + tid;               // < 4096
            int row = item >> 4, seg = item & 15;
            uint2 v = *(const uint2*)&t[row][seg * 4];
            *(uint2*)(xt + ((size_t)n * P_TOT + hw0 + row) * CI + cblk * 64 + seg * 4) = v;
        }
    } else {
        // wt swizzled: slot s = k*2048 + o*16 + csw holds 8 ch of c-seg
        // cs = csw ^ (o&7), i.e. LDS linear fill == swizzled layout.
        int s = (bid - 576) * 256 + tid;            // < 18432
        int k   = s >> 11;
        int r2  = s & 2047;
        int o   = r2 >> 4;
        int csw = r2 & 15;
        int cs  = csw ^ (o & 7);
        const float* src = w + (size_t)o * (CI * K2) + cs * 8 * K2 + k;
        ushort tmp[8];
        #pragma unroll
        for (int j = 0; j < 8; ++j) tmp[j] = bf16_rne(src[j * K2]);
        *(uint4*)&wt[(size_t)s * 8] = *(uint4*)tmp;
    }
}

__global__ __launch_bounds__(256, 2)
void dcn_mfma4_kernel(const ushort* __restrict__ xt,
                      const ushort* __restrict__ wt,
                      const float* __restrict__ offset,
                      const float* __restrict__ mask,
                      const float* __restrict__ bias,
                      float* __restrict__ out)
{
    __shared__ uint2  s_midx[K2 * TP];       // packed corner row indices
    __shared__ float4 s_mw[K2 * TP];         // bilinear*mask weights
    __shared__ ushort s_w[2][CO * CI];       // dbuf tap slab, swizzled, 2x32KB

    const int tid  = threadIdx.x;
    const int bid  = blockIdx.x;
    const int n    = bid & 7;                // XCD swizzle
    const int p0   = (bid >> 3) * TP;
    const int wave = tid >> 6;
    const int lane = tid & 63;
    const int l15  = lane & 15;
    const int quad = lane >> 4;

    // async-stage one tap slab (2048 slots of 16B; 8 issues/wave)
    auto stage = [&](int k, int buf) {
        const ushort* g = wt + ((size_t)k * 2048 + wave * 512) * 8;
        ushort* l = &s_w[buf][wave * 512 * 8];
        #pragma unroll
        for (int i = 0; i < 8; ++i)
            gll16(g + (size_t)(i * 64 + lane) * 8, l + i * 64 * 8);
    };

    stage(0, 0);        // tap 0 in flight under meta phase

    // ---- meta phase ----
    for (int it = 0; it < 3; ++it) {
        int item = it * 256 + tid;          // k*TP + i, < 576
        if (item < K2 * TP) {
            int k = item / TP;
            int i = item % TP;
            int p  = p0 + i;
            int ph = p / WI;
            int pw = p % WI;
            float offy = offset[((size_t)n * (2 * K2) + 2 * k    ) * P_TOT + p];
            float offx = offset[((size_t)n * (2 * K2) + 2 * k + 1) * P_TOT + p];
            float m    = mask  [((size_t)n * K2 + k) * P_TOT + p];
            int ky = k / 3, kx = k % 3;
            float py = (float)(ph - 1 + ky) + offy;
            float px = (float)(pw - 1 + kx) + offx;
            float y0f = floorf(py), x0f = floorf(px);
            float wy = py - y0f, wx = px - x0f;
            int y0 = (int)y0f, x0 = (int)x0f;
            int y1 = y0 + 1,  x1 = x0 + 1;
            bool vy0 = (y0 >= 0) && (y0 < HI);
            bool vy1 = (y1 >= 0) && (y1 < HI);
            bool vx0 = (x0 >= 0) && (x0 < WI);
            bool vx1 = (x1 >= 0) && (x1 < WI);
            unsigned i00 = (vy0 && vx0) ? (unsigned)(y0 * WI + x0) : 0u;
            unsigned i01 = (vy0 && vx1) ? (unsigned)(y0 * WI + x1) : 0u;
            unsigned i10 = (vy1 && vx0) ? (unsigned)(y1 * WI + x0) : 0u;
            unsigned i11 = (vy1 && vx1) ? (unsigned)(y1 * WI + x1) : 0u;
            float w00 = (vy0 && vx0) ? (1.f - wy) * (1.f - wx) * m : 0.f;
            float w01 = (vy0 && vx1) ? (1.f - wy) * wx          * m : 0.f;
            float w10 = (vy1 && vx0) ? wy * (1.f - wx)          * m : 0.f;
            float w11 = (vy1 && vx1) ? wy * wx                  * m : 0.f;
            s_midx[item] = make_uint2(i00 | (i01 << 16), i10 | (i11 << 16));
            s_mw[item]   = make_float4(w00, w01, w10, w11);
        }
    }
    __syncthreads();    // meta visible + tap0 slab landed (vmcnt drained)

    f32x4 acc[8];
    #pragma unroll
    for (int a = 0; a < 8; ++a) acc[a] = (f32x4){0.f, 0.f, 0.f, 0.f};

    const ushort* xb = xt + (size_t)n * (P_TOT * CI) + quad * 8;

    for (int k = 0; k < K2; ++k) {
        const int buf = k & 1;
        if (k < 8) stage(k + 1, buf ^ 1);   // async, in flight across this tap

        uint2  mi = s_midx[k * TP + wave * 16 + l15];
        float4 mw = s_mw[k * TP + wave * 16 + l15];
        const ushort* c00 = xb + (size_t)(mi.x & 0xFFFF) * CI;
        const ushort* c01 = xb + (size_t)(mi.x >> 16)    * CI;
        const ushort* c10 = xb + (size_t)(mi.y & 0xFFFF) * CI;
        const ushort* c11 = xb + (size_t)(mi.y >> 16)    * CI;

        uint4 ra[4], rb[4];
        ra[0] = *(const uint4*)(c00);      ra[1] = *(const uint4*)(c01);
        ra[2] = *(const uint4*)(c10);      ra[3] = *(const uint4*)(c11);
        rb[0] = *(const uint4*)(c00 + 32); rb[1] = *(const uint4*)(c01 + 32);
        rb[2] = *(const uint4*)(c10 + 32); rb[3] = *(const uint4*)(c11 + 32);

        #pragma unroll
        for (int cb = 0; cb < 4; ++cb) {
            uint4 r0 = (cb & 1) ? rb[0] : ra[0];
            uint4 r1 = (cb & 1) ? rb[1] : ra[1];
            uint4 r2 = (cb & 1) ? rb[2] : ra[2];
            uint4 r3 = (cb & 1) ? rb[3] : ra[3];
            float v0 = mw.x * bflo(r0.x) + mw.y * bflo(r1.x) + mw.z * bflo(r2.x) + mw.w * bflo(r3.x);
            float v1 = mw.x * bfhi(r0.x) + mw.y * bfhi(r1.x) + mw.z * bfhi(r2.x) + mw.w * bfhi(r3.x);
            float v2 = mw.x * bflo(r0.y) + mw.y * bflo(r1.y) + mw.z * bflo(r2.y) + mw.w * bflo(r3.y);
            float v3 = mw.x * bfhi(r0.y) + mw.y * bfhi(r1.y) + mw.z * bfhi(r2.y) + mw.w * bfhi(r3.y);
            float v4 = mw.x * bflo(r0.z) + mw.y * bflo(r1.z) + mw.z * bflo(r2.z) + mw.w * bflo(r3.z);
            float v5 = mw.x * bfhi(r0.z) + mw.y * bfhi(r1.z) + mw.z * bfhi(r2.z) + mw.w * bfhi(r3.z);
            float v6 = mw.x * bflo(r0.w) + mw.y * bflo(r1.w) + mw.z * bflo(r2.w) + mw.w * bflo(r3.w);
            float v7 = mw.x * bfhi(r0.w) + mw.y * bfhi(r1.w) + mw.z * bfhi(r2.w) + mw.w * bfhi(r3.w);
            if (cb == 0) {
                ra[0] = *(const uint4*)(c00 + 64); ra[1] = *(const uint4*)(c01 + 64);
                ra[2] = *(const uint4*)(c10 + 64); ra[3] = *(const uint4*)(c11 + 64);
            } else if (cb == 1) {
                rb[0] = *(const uint4*)(c00 + 96); rb[1] = *(const uint4*)(c01 + 96);
                rb[2] = *(const uint4*)(c10 + 96); rb[3] = *(const uint4*)(c11 + 96);
            }
            U4S8 cvt;
            cvt.u.x = pack_bf2(v0, v1);
            cvt.u.y = pack_bf2(v2, v3);
            cvt.u.z = pack_bf2(v4, v5);
            cvt.u.w = pack_bf2(v6, v7);
            short8 bfr = cvt.s;
            #pragma unroll
            for (int ot = 0; ot < 8; ++ot) {
                int o = ot * 16 + l15;
                short8 afr = *(const short8*)&s_w[buf][o * CI + (((cb * 4 + quad) ^ (o & 7)) * 8)];
                acc[ot] = __builtin_amdgcn_mfma_f32_16x16x32_bf16(afr, bfr, acc[ot], 0, 0, 0);
            }
        }
        __syncthreads();    // waves done with buf; next slab landed (vmcnt)
    }

    // ---- epilogue ----
    #pragma unroll
    for (int ot = 0; ot < 8; ++ot) {
        #pragma unroll
        for (int r = 0; r < 4; ++r) {
            int o = ot * 16 + quad * 4 + r;
            int p = p0 + wave * 16 + l15;
            out[((size_t)n * CO + o) * P_TOT + p] = acc[ot][r] + bias[o];
        }
    }
}

// ---------------- fallback (no workspace): round-2 structure ----------------
__global__ __launch_bounds__(256, 3)
void dcn_fallback_kernel(const float* __restrict__ x,
                         const float* __restrict__ offset,
                         const float* __restrict__ mask,
                         const float* __restrict__ weight,
                         const float* __restrict__ bias,
                         float* __restrict__ out)
{
    __shared__ uint2  s_midx[K2 * TP];
    __shared__ float4 s_mw[K2 * TP];
    __shared__ ushort s_v[TP * CPAD];
    __shared__ ushort s_w[CO * CPAD];

    const int tid  = threadIdx.x;
    const int bid  = blockIdx.x;
    const int n    = bid & 7;
    const int p0   = (bid >> 3) * TP;

    for (int it = 0; it < 3; ++it) {
        int item = it * 256 + tid;
        if (item < K2 * TP) {
            int k = item / TP;
            int i = item % TP;
            int p  = p0 + i;
            int ph = p / WI;
            int pw = p % WI;
            float offy = offset[((size_t)n * (2 * K2) + 2 * k    ) * P_TOT + p];
            float offx = offset[((size_t)n * (2 * K2) + 2 * k + 1) * P_TOT + p];
            float m    = mask  [((size_t)n * K2 + k) * P_TOT + p];
            int ky = k / 3, kx = k % 3;
            float py = (float)(ph - 1 + ky) + offy;
            float px = (float)(pw - 1 + kx) + offx;
            float y0f = floorf(py), x0f = floorf(px);
            float wy = py - y0f, wx = px - x0f;
            int y0 = (int)y0f, x0 = (int)x0f;
            int y1 = y0 + 1,  x1 = x0 + 1;
            bool vy0 = (y0 >= 0) && (y0 < HI);
            bool vy1 = (y1 >= 0) && (y1 < HI);
            bool vx0 = (x0 >= 0) && (x0 < WI);
            bool vx1 = (x1 >= 0) && (x1 < WI);
            unsigned i00 = (vy0 && vx0) ? (unsigned)(y0 * WI + x0) : 0u;
            unsigned i01 = (vy0 && vx1) ? (unsigned)(y0 * WI + x1) : 0u;
            unsigned i10 = (vy1 && vx0) ? (unsigned)(y1 * WI + x0) : 0u;
            unsigned i11 = (vy1 && vx1) ? (unsigned)(y1 * WI + x1) : 0u;
            float w00 = (vy0 && vx0) ? (1.f - wy) * (1.f - wx) * m : 0.f;
            float w01 = (vy0 && vx1) ? (1.f - wy) * wx          * m : 0.f;
            float w10 = (vy1 && vx0) ? wy * (1.f - wx)          * m : 0.f;
            float w11 = (vy1 && vx1) ? wy * wx                  * m : 0.f;
            s_midx[item] = make_uint2(i00 | (i01 << 16), i10 | (i11 << 16));
            s_mw[item]   = make_float4(w00, w01, w10, w11);
        }
    }
    __syncthreads();

    const int wave = tid >> 6;
    const int lane = tid & 63;
    const int l15  = lane & 15;
    const int quad = lane >> 4;
    const int o_base = (wave >> 1) * 64;
    const int p_base = (wave & 1) * 32;
    const int gp = tid & 63;
    const int cg = wave;

    f32x4 acc[4][2];
    #pragma unroll
    for (int a = 0; a < 4; ++a)
        #pragma unroll
        for (int b = 0; b < 2; ++b) acc[a][b] = (f32x4){0.f, 0.f, 0.f, 0.f};

    for (int cb = 0; cb < 4; ++cb) {
        for (int k = 0; k < K2; ++k) {
            {
                uint2  mi = s_midx[k * TP + gp];
                float4 mw = s_mw[k * TP + gp];
                int i00 = mi.x & 0xFFFF, i01 = mi.x >> 16;
                int i10 = mi.y & 0xFFFF, i11 = mi.y >> 16;
                const float* xb = x + ((size_t)(n * CI + cb * 32 + cg * 8)) * (HI * WI);
                float v[8];
                #pragma unroll
                for (int j = 0; j < 8; ++j) {
                    const float* xp = xb + (size_t)j * (HI * WI);
                    v[j] = mw.x * xp[i00] + mw.y * xp[i01]
                         + mw.z * xp[i10] + mw.w * xp[i11];
                }
                uint4 pk;
                pk.x = pack_bf2(v[0], v[1]);
                pk.y = pack_bf2(v[2], v[3]);
                pk.z = pack_bf2(v[4], v[5]);
                pk.w = pack_bf2(v[6], v[7]);
                *(uint4*)&s_v[gp * CPAD + cg * 8] = pk;
            }
            {
                int o = tid >> 1, half = tid & 1;
                const float* wsrc = weight + (size_t)o * (CI * K2)
                                  + (cb * 32 + half * 16) * K2 + k;
                ushort tmp[16];
                #pragma unroll
                for (int i = 0; i < 16; ++i) tmp[i] = bf16_rne(wsrc[i * K2]);
                *(uint4*)&s_w[o * CPAD + half * 16]     = *(uint4*)&tmp[0];
                *(uint4*)&s_w[o * CPAD + half * 16 + 8] = *(uint4*)&tmp[8];
            }
            __syncthreads();
            short8 afr[4], bfr[2];
            #pragma unroll
            for (int ot = 0; ot < 4; ++ot)
                afr[ot] = *(const short8*)&s_w[(o_base + ot * 16 + l15) * CPAD + quad * 8];
            #pragma unroll
            for (int pt = 0; pt < 2; ++pt)
                bfr[pt] = *(const short8*)&s_v[(p_base + pt * 16 + l15) * CPAD + quad * 8];
            #pragma unroll
            for (int ot = 0; ot < 4; ++ot)
                #pragma unroll
                for (int pt = 0; pt < 2; ++pt)
                    acc[ot][pt] = __builtin_amdgcn_mfma_f32_16x16x32_bf16(
                        afr[ot], bfr[pt], acc[ot][pt], 0, 0, 0);
            __syncthreads();
        }
    }

    #pragma unroll
    for (int ot = 0; ot < 4; ++ot)
        #pragma unroll
        for (int r = 0; r < 4; ++r) {
            int o = o_base + ot * 16 + quad * 4 + r;
            float b = bias[o];
            #pragma unroll
            for (int pt = 0; pt < 2; ++pt) {
                int p = p0 + p_base + pt * 16 + l15;
                out[((size_t)n * CO + o) * P_TOT + p] = acc[ot][pt][r] + b;
            }
        }
}

extern "C" void kernel_launch(void* const* d_in, const int* in_sizes, int n_in,
                              void* d_out, int out_size, void* d_ws, size_t ws_size,
                              hipStream_t stream) {
    const float* x      = (const float*)d_in[0];
    const float* offset = (const float*)d_in[1];
    const float* mask   = (const float*)d_in[2];
    const float* weight = (const float*)d_in[3];
    const float* bias   = (const float*)d_in[4];
    float* out = (float*)d_out;

    dim3 block(256);
    if (ws_size >= WS_NEED) {
        ushort* xt = (ushort*)d_ws;
        ushort* wt = xt + XT_ELEMS;
        pre_kernel<<<dim3(576 + 72), block, 0, stream>>>(x, weight, xt, wt);
        dcn_mfma4_kernel<<<dim3(NI * NTILE), block, 0, stream>>>(
            xt, wt, offset, mask, bias, out);
    } else {
        dcn_fallback_kernel<<<dim3(NI * NTILE), block, 0, stream>>>(
            x, offset, mask, weight, bias, out);
    }
}